// Round 3
// baseline (117.160 us; speedup 1.0000x reference)
//
#include <hip/hip_runtime.h>
#include <math.h>

// Problem constants (B=8, N=2048, F=64, O=64), f32 in/out.
#define BB 8
#define NN 2048
#define FF 64
#define OO 64
constexpr float ALPHA = 0.2f;

typedef float  f32x4  __attribute__((ext_vector_type(4)));
typedef short  s16x8  __attribute__((ext_vector_type(8)));
typedef unsigned int u32x4 __attribute__((ext_vector_type(4)));

// round-to-nearest-even f32 -> bf16, two at a time packed into a u32
static __device__ __forceinline__ unsigned int packbf2(float a, float b) {
    unsigned int ua = __builtin_bit_cast(unsigned int, a);
    unsigned int ub = __builtin_bit_cast(unsigned int, b);
    ua = (ua + 0x7FFFu + ((ua >> 16) & 1u)) >> 16;
    ub = (ub + 0x7FFFu + ((ub >> 16) & 1u)) & 0xFFFF0000u;
    return ua | ub;
}

// ---------------------------------------------------------------------------
// K1: dInv[row] = 1/sqrt(1 + sum_m A[row,m]).  One block per row.
// Read-only pass over A -> leaves A L3-resident for k_main.
// ---------------------------------------------------------------------------
__global__ __launch_bounds__(256) void k_rowsum(const float* __restrict__ A,
                                                float* __restrict__ dInv) {
    const int row = blockIdx.x;
    const float* a = A + (size_t)row * NN;
    const int t = threadIdx.x;

    float4 v0 = *(const float4*)(a + t * 4);
    float4 v1 = *(const float4*)(a + t * 4 + 1024);
    float s = v0.x + v0.y + v0.z + v0.w + v1.x + v1.y + v1.z + v1.w;

    #pragma unroll
    for (int off = 32; off > 0; off >>= 1) s += __shfl_down(s, off, 64);

    __shared__ float partial[4];
    const int lane = t & 63, w = t >> 6;
    if (lane == 0) partial[w] = s;
    __syncthreads();
    if (t == 0) {
        float tot = partial[0] + partial[1] + partial[2] + partial[3] + 1.0f;
        dInv[row] = 1.0f / sqrtf(tot);
    }
}

// ---------------------------------------------------------------------------
// K2: Y[row,o] = dInv[row] * sum_f X[row,f] * W[f,o]
//     writes Yf   [b][n][o]  f32   (self-term for the epilogue)
//     writes Ytb  [b][o][m]  bf16  (transposed; k_main's B-operand, L2-resident:
//                                   256 KB per batch)
// ---------------------------------------------------------------------------
__global__ __launch_bounds__(256) void k_xw(const float* __restrict__ X,
                                            const float* __restrict__ W,
                                            const float* __restrict__ dInv,
                                            float* __restrict__ Yf,
                                            ushort* __restrict__ Ytb) {
    __shared__ float Ws[FF][OO];   // 16 KB
    __shared__ float Xs[16][FF];   // 4 KB
    const int t = threadIdx.x;
    const int r0 = blockIdx.x * 16;

    #pragma unroll
    for (int j = 0; j < 4; ++j) {
        int f4 = t + 256 * j;
        ((float4*)Ws)[f4] = ((const float4*)W)[f4];
    }
    ((float4*)Xs)[t] = ((const float4*)(X + (size_t)r0 * FF))[t];
    __syncthreads();

    const int c = t & 63, g = t >> 6;
    float acc[4] = {0.f, 0.f, 0.f, 0.f};
    for (int f = 0; f < FF; ++f) {
        float wv = Ws[f][c];
        #pragma unroll
        for (int i = 0; i < 4; ++i) acc[i] += Xs[g * 4 + i][f] * wv;
    }
    float y[4];
    #pragma unroll
    for (int i = 0; i < 4; ++i) {
        int row = r0 + g * 4 + i;
        y[i] = dInv[row] * acc[i];
        Yf[(size_t)row * OO + c] = y[i];
    }
    const int b = r0 >> 11;           // 2048 rows per batch
    const int n = (r0 & (NN - 1)) + g * 4;
    unsigned int p0 = packbf2(y[0], y[1]);
    unsigned int p1 = packbf2(y[2], y[3]);
    *(uint2*)(Ytb + ((size_t)b * OO + c) * NN + n) = make_uint2(p0, p1);
}

// ---------------------------------------------------------------------------
// K3 (MFMA, barrier-free streaming):
//   out0[b,n,o] = leaky( dInv[n]*(sum_m A[n,m]*Y[m,o] + Y[n,o]) + bias[o] )
//   outA = copy of A (fused with the A fragment loads; each ct-half wave
//          writes its half of the K-range -> balanced, full coverage).
// Grid: 512 blocks x 256 thr (4 waves). Wave (rt = w>>1, ct = w&1) owns a
// 16-row x 32-col output tile; block covers 32 rows x 64 cols.
// Fragments load DIRECTLY from global: A rows are single-use (no LDS value),
// Y^T is 256 KB/batch bf16 -> L2-hot. No __syncthreads anywhere -> compiler
// pipelines loads across the unrolled K loop.
// Per K-step-32: 2x dwordx4 A (f32) + 2x dwordx4 Y^T (bf16) + 2 MFMA.
// ---------------------------------------------------------------------------
__global__ __launch_bounds__(256) void k_main(const float* __restrict__ A,
                                              const ushort* __restrict__ Ytb,
                                              const float* __restrict__ Yf,
                                              const float* __restrict__ dInv,
                                              const float* __restrict__ bias,
                                              float* __restrict__ out0,
                                              float* __restrict__ outA) {
    const int bx = blockIdx.x;
    const int b  = bx >> 6;
    const int n0 = (bx & 63) * 32;

    const int t = threadIdx.x;
    const int lane = t & 63, w = t >> 6;
    const int rt = w >> 1;           // row sub-tile (0/1)
    const int ct = w & 1;            // col half (0/1)
    const int fr = lane & 15, fg = lane >> 4;

    // A fragment row for this lane (16x16x32 A map: lane(fr,fg) holds
    // A[fr][fg*8 .. +7] of the 16x32 sub-block)
    const int arow = n0 + rt * 16 + fr;
    const float*  aRow = A    + ((size_t)b * NN + arow) * NN + fg * 8;
    float*        cRow = outA + ((size_t)b * NN + arow) * NN + fg * 8;

    // B fragments: Y^T rows = output cols (verified-by-pass mapping from R2)
    const ushort* yb    = Ytb + (size_t)b * OO * NN;
    const ushort* y0Row = yb + (size_t)(ct * 32 +      fr) * NN + fg * 8;
    const ushort* y1Row = yb + (size_t)(ct * 32 + 16 + fr) * NN + fg * 8;

    const int kw0 = ct * (NN / 2);   // this wave's A-copy K half

    f32x4 acc0 = {0.f, 0.f, 0.f, 0.f};
    f32x4 acc1 = {0.f, 0.f, 0.f, 0.f};

    #pragma unroll 4
    for (int k0 = 0; k0 < NN; k0 += 32) {
        float4 pa0 = *(const float4*)(aRow + k0);
        float4 pa1 = *(const float4*)(aRow + k0 + 4);
        s16x8  bf0 = *(const s16x8*)(y0Row + k0);
        s16x8  bf1 = *(const s16x8*)(y1Row + k0);

        if ((unsigned)(k0 - kw0) < (unsigned)(NN / 2)) {   // wave-uniform
            *(float4*)(cRow + k0)     = pa0;
            *(float4*)(cRow + k0 + 4) = pa1;
        }

        u32x4 qa;
        qa.x = packbf2(pa0.x, pa0.y);
        qa.y = packbf2(pa0.z, pa0.w);
        qa.z = packbf2(pa1.x, pa1.y);
        qa.w = packbf2(pa1.z, pa1.w);
        s16x8 af = __builtin_bit_cast(s16x8, qa);

        acc0 = __builtin_amdgcn_mfma_f32_16x16x32_bf16(af, bf0, acc0, 0, 0, 0);
        acc1 = __builtin_amdgcn_mfma_f32_16x16x32_bf16(af, bf1, acc1, 0, 0, 0);
    }

    // epilogue: D map col = lane&15, row = (lane>>4)*4 + reg (verified)
    const float*  Yf_b = Yf   + (size_t)b * NN * OO;
    float*        O_b  = out0 + (size_t)b * NN * OO;
    const float bv0 = bias[ct * 32 + fr];
    const float bv1 = bias[ct * 32 + 16 + fr];
    #pragma unroll
    for (int r = 0; r < 4; ++r) {
        const int nrow = n0 + rt * 16 + fg * 4 + r;
        const float di = dInv[(size_t)b * NN + nrow];
        {
            const int col = ct * 32 + fr;
            float v = di * (acc0[r] + Yf_b[(size_t)nrow * OO + col]) + bv0;
            O_b[(size_t)nrow * OO + col] = (v >= 0.f) ? v : ALPHA * v;
        }
        {
            const int col = ct * 32 + 16 + fr;
            float v = di * (acc1[r] + Yf_b[(size_t)nrow * OO + col]) + bv1;
            O_b[(size_t)nrow * OO + col] = (v >= 0.f) ? v : ALPHA * v;
        }
    }
}

// ---------------------------------------------------------------------------
extern "C" void kernel_launch(void* const* d_in, const int* in_sizes, int n_in,
                              void* d_out, int out_size, void* d_ws, size_t ws_size,
                              hipStream_t stream) {
    const float* X    = (const float*)d_in[0];
    const float* A    = (const float*)d_in[1];
    const float* W    = (const float*)d_in[2];
    const float* bias = (const float*)d_in[3];

    float* out0 = (float*)d_out;                       // [B,N,O]
    float* outA = out0 + (size_t)BB * NN * OO;         // [B,N,N]

    float*  dInv = (float*)d_ws;                       // 16384 f32 (64 KB)
    float*  Yf   = dInv + (size_t)BB * NN;             // 4 MB
    ushort* Ytb  = (ushort*)(Yf + (size_t)BB * NN * OO); // 2 MB

    k_rowsum<<<BB * NN, 256, 0, stream>>>(A, dInv);
    k_xw    <<<BB * NN / 16, 256, 0, stream>>>(X, W, dInv, Yf, Ytb);
    k_main  <<<BB * 64, 256, 0, stream>>>(A, Ytb, Yf, dInv, bias, out0, outA);
}

// Round 4
// 85.893 us; speedup vs baseline: 1.3640x; 1.3640x over previous
//
#include <hip/hip_runtime.h>
#include <math.h>

// Problem constants (B=8, N=2048, F=64, O=64), f32 in/out.
#define BB 8
#define NN 2048
#define FF 64
#define OO 64
#define KC 128                 // K-chunk per iteration
#define NITER (NN / KC)        // 16
constexpr float ALPHA = 0.2f;

typedef float  f32x4  __attribute__((ext_vector_type(4)));
typedef short  s16x8  __attribute__((ext_vector_type(8)));

// round-to-nearest-even f32 -> bf16, two packed into a u32
static __device__ __forceinline__ unsigned int packbf2(float a, float b) {
    unsigned int ua = __builtin_bit_cast(unsigned int, a);
    unsigned int ub = __builtin_bit_cast(unsigned int, b);
    ua = (ua + 0x7FFFu + ((ua >> 16) & 1u)) >> 16;
    ub = (ub + 0x7FFFu + ((ub >> 16) & 1u)) & 0xFFFF0000u;
    return ua | ub;
}

// ---------------------------------------------------------------------------
// K1: dInv[row] = 1/sqrt(1 + sum_m A[row,m]).  One block per row.
// ---------------------------------------------------------------------------
__global__ __launch_bounds__(256) void k_rowsum(const float* __restrict__ A,
                                                float* __restrict__ dInv) {
    const int row = blockIdx.x;
    const float* a = A + (size_t)row * NN;
    const int t = threadIdx.x;

    float4 v0 = *(const float4*)(a + t * 4);
    float4 v1 = *(const float4*)(a + t * 4 + 1024);
    float s = v0.x + v0.y + v0.z + v0.w + v1.x + v1.y + v1.z + v1.w;

    #pragma unroll
    for (int off = 32; off > 0; off >>= 1) s += __shfl_down(s, off, 64);

    __shared__ float partial[4];
    const int lane = t & 63, w = t >> 6;
    if (lane == 0) partial[w] = s;
    __syncthreads();
    if (t == 0) {
        float tot = partial[0] + partial[1] + partial[2] + partial[3] + 1.0f;
        dInv[row] = 1.0f / sqrtf(tot);
    }
}

// ---------------------------------------------------------------------------
// K2: Y[row,o] = dInv[row] * sum_f X[row,f] * W[f,o]
//     Yf  [b][n][o] f32  (self-term for epilogue)
//     Ytb [b][o][m] bf16 (transposed; k_main B-operand, L2-resident 256KB/batch)
// ---------------------------------------------------------------------------
__global__ __launch_bounds__(256) void k_xw(const float* __restrict__ X,
                                            const float* __restrict__ W,
                                            const float* __restrict__ dInv,
                                            float* __restrict__ Yf,
                                            ushort* __restrict__ Ytb) {
    __shared__ float Ws[FF][OO];
    __shared__ float Xs[16][FF];
    const int t = threadIdx.x;
    const int r0 = blockIdx.x * 16;

    #pragma unroll
    for (int j = 0; j < 4; ++j) {
        int f4 = t + 256 * j;
        ((float4*)Ws)[f4] = ((const float4*)W)[f4];
    }
    ((float4*)Xs)[t] = ((const float4*)(X + (size_t)r0 * FF))[t];
    __syncthreads();

    const int c = t & 63, g = t >> 6;
    float acc[4] = {0.f, 0.f, 0.f, 0.f};
    for (int f = 0; f < FF; ++f) {
        float wv = Ws[f][c];
        #pragma unroll
        for (int i = 0; i < 4; ++i) acc[i] += Xs[g * 4 + i][f] * wv;
    }
    float y[4];
    #pragma unroll
    for (int i = 0; i < 4; ++i) {
        int row = r0 + g * 4 + i;
        y[i] = dInv[row] * acc[i];
        Yf[(size_t)row * OO + c] = y[i];
    }
    const int b = r0 >> 11;
    const int n = (r0 & (NN - 1)) + g * 4;
    unsigned int p0 = packbf2(y[0], y[1]);
    unsigned int p1 = packbf2(y[2], y[3]);
    *(uint2*)(Ytb + ((size_t)b * OO + c) * NN + n) = make_uint2(p0, p1);
}

// ---------------------------------------------------------------------------
// K3 (MFMA): out0[b,n,o] = leaky( dInv[n]*(sum_m A[n,m]*Y[m,o] + Y[n,o]) + bias[o] )
//            outA = copy of A (fused with A staging loads).
// 1024 blocks (16 rows x 64 cols each) x 256 thr (4 waves) -> 4 blocks/CU.
// Wave w owns the 16x16 tile at cols w*16. K-chunk 128, 16 iterations.
// As: [16][136] ushort (272 B rows -> 4-bank rotation, <=2-way reads).
// Ys: linear [64 rows][256 B] with XOR swizzle byte^=((row&7)<<4): write swz,
//     read swz -> <=2-way conflicts (free). Register prefetch of next tile
//     issued right after barrier 2 (overlaps MFMA + other blocks).
// ---------------------------------------------------------------------------
__global__ __launch_bounds__(256, 4) void k_main(const float* __restrict__ A,
                                                 const ushort* __restrict__ Ytb,
                                                 const float* __restrict__ Yf,
                                                 const float* __restrict__ dInv,
                                                 const float* __restrict__ bias,
                                                 float* __restrict__ out0,
                                                 float* __restrict__ outA) {
    __shared__ ushort As[16][136];     // 4.25 KB
    __shared__ ushort Ys[64 * 128];    // 16 KB, logical [o][128 K-elems], swizzled

    const int bx = blockIdx.x;          // 1024
    const int b  = bx >> 7;             // 128 row-tiles per batch
    const int n0 = (bx & 127) * 16;

    const float*  Ab   = A    + ((size_t)b * NN + n0) * NN;
    float*        Cb   = outA + ((size_t)b * NN + n0) * NN;
    const ushort* yb   = Ytb  + (size_t)b * OO * NN;
    const float*  Yf_b = Yf   + (size_t)b * NN * OO;
    float*        O_b  = out0 + (size_t)b * NN * OO;

    const int t = threadIdx.x;
    const int lane = t & 63, w = t >> 6;
    const int fr = lane & 15, fg = lane >> 4;

    // ---- A staging coords (2 float4/thread): f4 = t + 256j ----
    const int ar0 = t >> 5,            ac0 = (t & 31) * 4;           // j=0
    const int ar1 = (t + 256) >> 5,    ac1 = (t & 31) * 4;           // j=1 (row +8)
    const float* aSrc0 = Ab + (size_t)ar0 * NN + ac0;
    const float* aSrc1 = Ab + (size_t)ar1 * NN + ac1;
    float*       aDst0 = Cb + (size_t)ar0 * NN + ac0;
    float*       aDst1 = Cb + (size_t)ar1 * NN + ac1;

    // ---- Y staging coords (4 uint4/thread): rows 16w+4j+(lane>>4) ----
    const int yrBase = w * 16 + (lane >> 4);       // + 4j
    const int ycu    = (lane & 15) * 8;            // ushort offset in K-slice
    // LDS dest ushort idx: row*128 + (ycu ^ ((row&7)<<3))

    // ---- fragment read bases ----
    // A: byte = fr*272 + ks*64 + fg*16  -> ushort idx fr*136 + ks*32 + fg*8
    const ushort* aFragBase = &As[fr][fg * 8];
    // B: ushort idx = (w*16+fr)*128 + ((ks*32 + fg*8) ^ ((fr&7)<<3))
    const int yRow  = w * 16 + fr;
    const int ySwz  = (fr & 7) << 3;

    f32x4 acc = {0.f, 0.f, 0.f, 0.f};

    float4 pa0, pa1;
    uint4  py0, py1, py2, py3;

    // prologue: prefetch tile 0
    pa0 = *(const float4*)(aSrc0);
    pa1 = *(const float4*)(aSrc1);
    {
        const ushort* s = yb + (size_t)yrBase * NN + ycu;
        py0 = *(const uint4*)(s);
        py1 = *(const uint4*)(s + 4 * NN);
        py2 = *(const uint4*)(s + 8 * NN);
        py3 = *(const uint4*)(s + 12 * NN);
    }

    for (int i = 0; i < NITER; ++i) {
        const int k0 = i * KC;
        __syncthreads();   // all waves done reading LDS from prev iter

        // ---- write phase: A copy-out + LDS fills ----
        *(float4*)(aDst0 + k0) = pa0;
        *(float4*)(aDst1 + k0) = pa1;
        {
            uint2 qa;
            qa.x = packbf2(pa0.x, pa0.y);
            qa.y = packbf2(pa0.z, pa0.w);
            *(uint2*)&As[ar0][ac0] = qa;
            qa.x = packbf2(pa1.x, pa1.y);
            qa.y = packbf2(pa1.z, pa1.w);
            *(uint2*)&As[ar1][ac1] = qa;
        }
        #pragma unroll
        for (int j = 0; j < 4; ++j) {
            const int row = yrBase + 4 * j;
            const int di  = row * 128 + (ycu ^ ((row & 7) << 3));
            *(uint4*)&Ys[di] = (j == 0) ? py0 : (j == 1) ? py1 : (j == 2) ? py2 : py3;
        }
        __syncthreads();   // LDS visible

        // ---- prefetch next tile (overlaps MFMA + other blocks) ----
        if (i + 1 < NITER) {
            const int kn = k0 + KC;
            pa0 = *(const float4*)(aSrc0 + kn);
            pa1 = *(const float4*)(aSrc1 + kn);
            const ushort* s = yb + (size_t)yrBase * NN + kn + ycu;
            py0 = *(const uint4*)(s);
            py1 = *(const uint4*)(s + 4 * NN);
            py2 = *(const uint4*)(s + 8 * NN);
            py3 = *(const uint4*)(s + 12 * NN);
        }

        // ---- MFMA phase: 4 K-substeps of 32 ----
        #pragma unroll
        for (int ks = 0; ks < 4; ++ks) {
            s16x8 af = *(const s16x8*)(aFragBase + ks * 32);
            s16x8 bf = *(const s16x8*)&Ys[yRow * 128 + ((ks * 32 + fg * 8) ^ ySwz)];
            acc = __builtin_amdgcn_mfma_f32_16x16x32_bf16(af, bf, acc, 0, 0, 0);
        }
    }

    // ---- epilogue: D map col = lane&15, row = (lane>>4)*4 + reg ----
    const int col = w * 16 + fr;
    const float bv = bias[col];
    #pragma unroll
    for (int r = 0; r < 4; ++r) {
        const int nrow = n0 + fg * 4 + r;
        const float di = dInv[(size_t)b * NN + nrow];
        float v = di * (acc[r] + Yf_b[(size_t)nrow * OO + col]) + bv;
        O_b[(size_t)nrow * OO + col] = (v >= 0.f) ? v : ALPHA * v;
    }
}

// ---------------------------------------------------------------------------
extern "C" void kernel_launch(void* const* d_in, const int* in_sizes, int n_in,
                              void* d_out, int out_size, void* d_ws, size_t ws_size,
                              hipStream_t stream) {
    const float* X    = (const float*)d_in[0];
    const float* A    = (const float*)d_in[1];
    const float* W    = (const float*)d_in[2];
    const float* bias = (const float*)d_in[3];

    float* out0 = (float*)d_out;                         // [B,N,O]
    float* outA = out0 + (size_t)BB * NN * OO;           // [B,N,N]

    float*  dInv = (float*)d_ws;                         // 64 KB
    float*  Yf   = dInv + (size_t)BB * NN;               // 4 MB
    ushort* Ytb  = (ushort*)(Yf + (size_t)BB * NN * OO); // 2 MB

    k_rowsum<<<BB * NN, 256, 0, stream>>>(A, dInv);
    k_xw    <<<BB * NN / 16, 256, 0, stream>>>(X, W, dInv, Yf, Ytb);
    k_main  <<<BB * 128, 256, 0, stream>>>(A, Ytb, Yf, dInv, bias, out0, outA);
}